// Round 6
// baseline (1776.450 us; speedup 1.0000x reference)
//
#include <hip/hip_runtime.h>

// ---------------------------------------------------------------------------
// DendriticMLP on MI355X — round 6.
// f16 hi/lo split GEMMs (3-term MFMA hh+hl+lh, ~2^-21 rel err): all discrete
// decisions (abs-max gating, top-k) match the fp32 reference.
// Dend GEMM redesign (LDS-port-bound diagnosis): B (seg) fragments are loaded
// DIRECTLY from frag-major pre-split f16 planes into registers (dense 1 KB
// coalesced loads, no LDS, no wave-duplication through LDS); A (ctx) staged
// via round-3's in-kernel split. LDS traffic/K-step drops 108 KB -> ~48 KB,
// below the MFMA floor. The next chunk's seg split is FUSED into the dend
// epilogue (ping-pong regions), removing 15 split launches.
// Workspace (<=85 MB of proven-96): gates1[0,32) gates2[32,64) pingpong
// planes [64,84); then yb[64,96), yb2=[0,32).
// ---------------------------------------------------------------------------

#define AS1 __attribute__((address_space(1)))
#define AS3 __attribute__((address_space(3)))

typedef _Float16 f16x8 __attribute__((ext_vector_type(8)));
typedef _Float16 f16x4 __attribute__((ext_vector_type(4)));
typedef float    f32x4 __attribute__((ext_vector_type(4)));

__device__ __forceinline__ int swz(int row, int q) {
    return row * 32 + ((q ^ ((row >> 1) & 3)) << 3);
}

// DMA chunks of a [rows][32]-halfword row-major tile into swizzled LDS
// (used by gemm_adma for the kwinners h planes).
__device__ __forceinline__ void dma_tile(const _Float16* __restrict__ g, long row0,
                                         int ldHalf, int kcol, _Float16* lds, int tid,
                                         int chunks) {
    for (int s = tid; s < chunks; s += 256) {
        const int row = s >> 2, cp = s & 3;
        const int src = cp ^ ((row >> 1) & 3);
        const _Float16* gp = g + (row0 + row) * (long)ldHalf + kcol + src * 8;
        __builtin_amdgcn_global_load_lds((const AS1 void*)gp,
                                         (AS3 void*)(lds + ((s & ~63) << 3)), 16, 0, 0);
    }
}

__device__ __forceinline__ void cvt_store(const float4 v, int c, _Float16* sH,
                                          _Float16* sL) {
    const int row = c >> 3, hc = c & 7;
    f16x4 h, l;
    h.x = (_Float16)v.x; l.x = (_Float16)(v.x - (float)h.x);
    h.y = (_Float16)v.y; l.y = (_Float16)(v.y - (float)h.y);
    h.z = (_Float16)v.z; l.z = (_Float16)(v.z - (float)h.z);
    h.w = (_Float16)v.w; l.w = (_Float16)(v.w - (float)h.w);
    const int off = row * 32 + (((hc >> 1) ^ ((row >> 1) & 3)) << 3) + ((hc & 1) << 2);
    *(f16x4*)(sH + off) = h;
    *(f16x4*)(sL + off) = l;
}

// ---------------------------------------------------------------------------
// Frag-major split: fp32 [2560][1024] chunk -> f16 hi/lo planes where slot
// s = ((rowtile*32 + kt)*64 + lane), lane = (q<<4)|l15, holds element
// (rowtile*16+l15, kt*32+q*8+j), j=0..7. One wave's MFMA B-frag = 1 KB dense.
// ---------------------------------------------------------------------------
__device__ __forceinline__ void split_slot(const float* __restrict__ src, int s,
                                           _Float16* __restrict__ H,
                                           _Float16* __restrict__ L) {
    const int lane = s & 63, tk = s >> 6;
    const int kt = tk & 31, t = tk >> 5;
    const int l15 = lane & 15, q = lane >> 4;
    const float* p = src + (long)(t * 16 + l15) * 1024 + kt * 32 + q * 8;
    const float4 a = *(const float4*)p;
    const float4 b = *(const float4*)(p + 4);
    f16x4 h0, l0, h1, l1;
    h0.x = (_Float16)a.x; l0.x = (_Float16)(a.x - (float)h0.x);
    h0.y = (_Float16)a.y; l0.y = (_Float16)(a.y - (float)h0.y);
    h0.z = (_Float16)a.z; l0.z = (_Float16)(a.z - (float)h0.z);
    h0.w = (_Float16)a.w; l0.w = (_Float16)(a.w - (float)h0.w);
    h1.x = (_Float16)b.x; l1.x = (_Float16)(b.x - (float)h1.x);
    h1.y = (_Float16)b.y; l1.y = (_Float16)(b.y - (float)h1.y);
    h1.z = (_Float16)b.z; l1.z = (_Float16)(b.z - (float)h1.z);
    h1.w = (_Float16)b.w; l1.w = (_Float16)(b.w - (float)h1.w);
    *(f16x4*)(H + (long)s * 8) = h0;
    *(f16x4*)(H + (long)s * 8 + 4) = h1;
    *(f16x4*)(L + (long)s * 8) = l0;
    *(f16x4*)(L + (long)s * 8 + 4) = l1;
}

__global__ __launch_bounds__(256) void split_frag(const float* __restrict__ src,
                                                  _Float16* __restrict__ H,
                                                  _Float16* __restrict__ L) {
    const int s = blockIdx.x * 256 + threadIdx.x;  // grid covers 327680 slots
    split_slot(src, s, H, L);
}

// ---------------------------------------------------------------------------
// Dendrite GEMM v6: tile 128(b) x 160(n), waves 2x2, wave 64x80 (4x5 accs).
// A = ctx fp32 in-kernel split -> swizzled LDS (round-3 proven two-barrier).
// B = frag-major f16 planes, per-K-step register loads (dense 1 KB/frag).
// Epilogue: abs-max over the 10 segments per h (strict > = jnp.argmax first
// occurrence), gates[b][hoff+h] = sigmoid(sel); then fused split of the NEXT
// seg chunk into the ping-pong region.
// ---------------------------------------------------------------------------
__global__ __launch_bounds__(256) void dend_gemm(
    const float* __restrict__ ctx, const _Float16* __restrict__ BH,
    const _Float16* __restrict__ BL, float* __restrict__ gates, int hoff,
    const float* __restrict__ srcNext, _Float16* __restrict__ nH,
    _Float16* __restrict__ nL) {
    __shared__ __align__(16) char smem[40960];
    _Float16* sAh = (_Float16*)smem;           // 8192 B (128x32)
    _Float16* sAl = (_Float16*)(smem + 8192);  // 8192 B
    float* Cred = (float*)smem;                // [64][160] epilogue union
    const int tid = threadIdx.x;
    const int w = tid >> 6, lane = tid & 63;
    const int wm = w >> 1, wn = w & 1;
    const int q = lane >> 4, l15 = lane & 15;
    const int bn = blockIdx.x, bm = blockIdx.y;
    const long arow0 = (long)bm * 128;
    const int bnt = bn * 10 + wn * 5;  // B row-tile base for this wave
    f32x4 acc[4][5] = {};
    float4 preA[4];
    auto loadA = [&](int kt) {
#pragma unroll
        for (int j = 0; j < 4; ++j) {
            const int c = tid + j * 256;
            preA[j] = *(const float4*)(ctx + (arow0 + (c >> 3)) * 1024L + (kt << 5) +
                                       ((c & 7) << 2));
        }
    };
    loadA(0);
    for (int kt = 0; kt < 32; ++kt) {
        __syncthreads();  // previous iteration's LDS frag reads complete
        // B fragments: dense register loads from frag-major planes
        f16x8 bH[5], bL[5];
#pragma unroll
        for (int tn = 0; tn < 5; ++tn) {
            const long slot = ((long)(bnt + tn) * 32 + kt) * 64 + lane;
            bH[tn] = *(const f16x8*)(BH + slot * 8);
            bL[tn] = *(const f16x8*)(BL + slot * 8);
        }
        // stage A (split in registers), prefetch next A
#pragma unroll
        for (int j = 0; j < 4; ++j) cvt_store(preA[j], tid + j * 256, sAh, sAl);
        if (kt < 31) loadA(kt + 1);
        __syncthreads();  // drains ds_writes + vmem (B regs ready)
        f16x8 aH[4], aL[4];
#pragma unroll
        for (int tm = 0; tm < 4; ++tm) {
            const int row = wm * 64 + tm * 16 + l15;
            aH[tm] = *(const f16x8*)&sAh[swz(row, q)];
            aL[tm] = *(const f16x8*)&sAl[swz(row, q)];
        }
#pragma unroll
        for (int tn = 0; tn < 5; ++tn) {
#pragma unroll
            for (int tm = 0; tm < 4; ++tm) {
                acc[tm][tn] = __builtin_amdgcn_mfma_f32_16x16x32_f16(aH[tm], bH[tn], acc[tm][tn], 0, 0, 0);
                acc[tm][tn] = __builtin_amdgcn_mfma_f32_16x16x32_f16(aH[tm], bL[tn], acc[tm][tn], 0, 0, 0);
                acc[tm][tn] = __builtin_amdgcn_mfma_f32_16x16x32_f16(aL[tm], bH[tn], acc[tm][tn], 0, 0, 0);
            }
        }
    }
    // epilogue: two 64-row chunks through LDS ([64][160]: hh*10 mod 32 distinct)
    for (int c = 0; c < 2; ++c) {
        __syncthreads();
        if (wm == c) {
#pragma unroll
            for (int tm = 0; tm < 4; ++tm)
#pragma unroll
                for (int tn = 0; tn < 5; ++tn)
#pragma unroll
                    for (int r = 0; r < 4; ++r)
                        Cred[(tm * 16 + q * 4 + r) * 160 + wn * 80 + tn * 16 + l15] =
                            acc[tm][tn][r];
        }
        __syncthreads();
        for (int p = tid; p < 1024; p += 256) {
            const int bb = p >> 4, hh = p & 15;
            const float* d = &Cred[bb * 160 + hh * 10];
            float best = d[0], ba = fabsf(d[0]);
#pragma unroll
            for (int s = 1; s < 10; ++s) {
                const float v = d[s], a = fabsf(v);
                if (a > ba) { ba = a; best = v; }  // strict >: first occurrence
            }
            const float gate = 1.f / (1.f + expf(-best));
            const int bg = bm * 128 + c * 64 + bb;
            gates[(long)bg * 2048 + hoff + bn * 16 + hh] = gate;
        }
    }
    // fused split of the next chunk (stream order guarantees visibility)
    if (srcNext) {
        const int base = (bm * 16 + bn) * 640;  // 512 blocks x 640 slots = 327680
        for (int i = tid; i < 640; i += 256) split_slot(srcNext, base + i, nH, nL);
    }
}

// ---------------------------------------------------------------------------
// GEMM, A = f16 hi/lo planes with row stride ldA halfwords (kwinners'
// row-interleaved layout), DMA-staged; B fp32 (prefetch + in-kernel split).
// ---------------------------------------------------------------------------
__global__ __launch_bounds__(256) void gemm_adma(
    const _Float16* __restrict__ AH, const _Float16* __restrict__ AL, int ldA,
    const float* __restrict__ B, const float* __restrict__ bias,
    float* __restrict__ C, int N, int K) {
    __shared__ __align__(16) _Float16 sAh[4096], sAl[4096], sBh[4096], sBl[4096];
    const int tid = threadIdx.x;
    const int w = tid >> 6, lane = tid & 63;
    const int wm = w >> 1, wn = w & 1;
    const int q = lane >> 4, l15 = lane & 15;
    const int bm = blockIdx.y, bn = blockIdx.x;
    const long arow0 = (long)bm * 128, brow0 = (long)bn * 128;
    f32x4 acc[4][4] = {};
    float4 pre[4];
    auto loadB = [&](int kt) {
#pragma unroll
        for (int j = 0; j < 4; ++j) {
            const int c = tid + j * 256;
            pre[j] = *(const float4*)(B + (brow0 + (c >> 3)) * (long)K + (kt << 5) +
                                      ((c & 7) << 2));
        }
    };
    loadB(0);
    const int ksteps = K >> 5;
    for (int kt = 0; kt < ksteps; ++kt) {
        __syncthreads();
        const int kcol = kt << 5;
        dma_tile(AH, arow0, ldA, kcol, sAh, tid, 512);
        dma_tile(AL, arow0, ldA, kcol, sAl, tid, 512);
#pragma unroll
        for (int j = 0; j < 4; ++j) cvt_store(pre[j], tid + j * 256, sBh, sBl);
        if (kt + 1 < ksteps) loadB(kt + 1);
        __syncthreads();
        f16x8 aH[4], aL[4];
#pragma unroll
        for (int tm = 0; tm < 4; ++tm) {
            const int row = wm * 64 + tm * 16 + l15;
            aH[tm] = *(const f16x8*)&sAh[swz(row, q)];
            aL[tm] = *(const f16x8*)&sAl[swz(row, q)];
        }
#pragma unroll
        for (int tn = 0; tn < 4; ++tn) {
            const int rowb = wn * 64 + tn * 16 + l15;
            const f16x8 bH = *(const f16x8*)&sBh[swz(rowb, q)];
            const f16x8 bL = *(const f16x8*)&sBl[swz(rowb, q)];
#pragma unroll
            for (int tm = 0; tm < 4; ++tm) {
                acc[tm][tn] = __builtin_amdgcn_mfma_f32_16x16x32_f16(aH[tm], bH, acc[tm][tn], 0, 0, 0);
                acc[tm][tn] = __builtin_amdgcn_mfma_f32_16x16x32_f16(aH[tm], bL, acc[tm][tn], 0, 0, 0);
                acc[tm][tn] = __builtin_amdgcn_mfma_f32_16x16x32_f16(aL[tm], bH, acc[tm][tn], 0, 0, 0);
            }
        }
    }
    float bv[4];
#pragma unroll
    for (int tn = 0; tn < 4; ++tn) bv[tn] = bias[bn * 128 + wn * 64 + tn * 16 + l15];
#pragma unroll
    for (int tm = 0; tm < 4; ++tm) {
        const int m0 = bm * 128 + wm * 64 + tm * 16 + q * 4;
#pragma unroll
        for (int tn = 0; tn < 4; ++tn) {
            const int n = bn * 128 + wn * 64 + tn * 16 + l15;
#pragma unroll
            for (int r = 0; r < 4; ++r)
                C[(long)(m0 + r) * N + n] = acc[tm][tn][r] + bv[tn];
        }
    }
}

// ---------------------------------------------------------------------------
// GEMM, A and B both fp32 (layer 1: x @ w1^T).
// ---------------------------------------------------------------------------
__global__ __launch_bounds__(256) void gemm_ab(
    const float* __restrict__ A, const float* __restrict__ B,
    const float* __restrict__ bias, float* __restrict__ C, int N, int K) {
    __shared__ __align__(16) _Float16 sAh[4096], sAl[4096], sBh[4096], sBl[4096];
    const int tid = threadIdx.x;
    const int w = tid >> 6, lane = tid & 63;
    const int wm = w >> 1, wn = w & 1;
    const int q = lane >> 4, l15 = lane & 15;
    const int bm = blockIdx.y, bn = blockIdx.x;
    const long arow0 = (long)bm * 128, brow0 = (long)bn * 128;
    f32x4 acc[4][4] = {};
    float4 preA[4], preB[4];
    auto loadAB = [&](int kt) {
#pragma unroll
        for (int j = 0; j < 4; ++j) {
            const int c = tid + j * 256;
            preA[j] = *(const float4*)(A + (arow0 + (c >> 3)) * (long)K + (kt << 5) +
                                       ((c & 7) << 2));
            preB[j] = *(const float4*)(B + (brow0 + (c >> 3)) * (long)K + (kt << 5) +
                                       ((c & 7) << 2));
        }
    };
    loadAB(0);
    const int ksteps = K >> 5;
    for (int kt = 0; kt < ksteps; ++kt) {
        __syncthreads();
#pragma unroll
        for (int j = 0; j < 4; ++j) {
            cvt_store(preA[j], tid + j * 256, sAh, sAl);
            cvt_store(preB[j], tid + j * 256, sBh, sBl);
        }
        if (kt + 1 < ksteps) loadAB(kt + 1);
        __syncthreads();
        f16x8 aH[4], aL[4];
#pragma unroll
        for (int tm = 0; tm < 4; ++tm) {
            const int row = wm * 64 + tm * 16 + l15;
            aH[tm] = *(const f16x8*)&sAh[swz(row, q)];
            aL[tm] = *(const f16x8*)&sAl[swz(row, q)];
        }
#pragma unroll
        for (int tn = 0; tn < 4; ++tn) {
            const int rowb = wn * 64 + tn * 16 + l15;
            const f16x8 bH = *(const f16x8*)&sBh[swz(rowb, q)];
            const f16x8 bL = *(const f16x8*)&sBl[swz(rowb, q)];
#pragma unroll
            for (int tm = 0; tm < 4; ++tm) {
                acc[tm][tn] = __builtin_amdgcn_mfma_f32_16x16x32_f16(aH[tm], bH, acc[tm][tn], 0, 0, 0);
                acc[tm][tn] = __builtin_amdgcn_mfma_f32_16x16x32_f16(aH[tm], bL, acc[tm][tn], 0, 0, 0);
                acc[tm][tn] = __builtin_amdgcn_mfma_f32_16x16x32_f16(aL[tm], bH, acc[tm][tn], 0, 0, 0);
            }
        }
    }
    float bv[4];
#pragma unroll
    for (int tn = 0; tn < 4; ++tn) bv[tn] = bias[bn * 128 + wn * 64 + tn * 16 + l15];
#pragma unroll
    for (int tm = 0; tm < 4; ++tm) {
        const int m0 = bm * 128 + wm * 64 + tm * 16 + q * 4;
#pragma unroll
        for (int tn = 0; tn < 4; ++tn) {
            const int n = bn * 128 + wn * 64 + tn * 16 + l15;
#pragma unroll
            for (int r = 0; r < 4; ++r)
                C[(long)(m0 + r) * N + n] = acc[tm][tn][r] + bv[tn];
        }
    }
}

// ---------------------------------------------------------------------------
// KWinners: v = y*gate (fp32); exact 102nd-largest via radix select on
// order-preserving uint keys; keep where key >= kth (jnp tie semantics).
// Writes h planes IN PLACE over y, row-interleaved (hi | lo per 8 KB row).
// ---------------------------------------------------------------------------
__global__ __launch_bounds__(256) void kwinners_kernel(float* __restrict__ y,
                                                       const float* __restrict__ g) {
    __shared__ unsigned hist[256];
    __shared__ unsigned scan[257];
    __shared__ int sb, srank;
    const int tid = threadIdx.x;
    const long base = (long)blockIdx.x * 2048;
    float v[8];
    unsigned u[8];
#pragma unroll
    for (int j = 0; j < 8; ++j) {
        const int i = j * 256 + tid;
        const float val = y[base + i] * g[base + i];
        v[j] = val;
        const unsigned b = __float_as_uint(val);
        u[j] = b ^ (unsigned)((((int)b) >> 31) | 0x80000000);  // monotone map
    }
    unsigned prefix = 0, pmask = 0;
    int rank = 102;
    for (int round = 0; round < 4; ++round) {
        const int shift = 24 - (round << 3);
        hist[tid] = 0;
        if (tid == 0) scan[256] = 0;
        __syncthreads();
#pragma unroll
        for (int j = 0; j < 8; ++j)
            if ((u[j] & pmask) == prefix) atomicAdd(&hist[(u[j] >> shift) & 255], 1u);
        __syncthreads();
        scan[tid] = hist[tid];
        __syncthreads();
        for (int off = 1; off < 256; off <<= 1) {  // inclusive suffix sum
            const unsigned t = scan[tid] + ((tid + off < 256) ? scan[tid + off] : 0u);
            __syncthreads();
            scan[tid] = t;
            __syncthreads();
        }
        if (scan[tid] >= (unsigned)rank && scan[tid + 1] < (unsigned)rank) {
            sb = tid;
            srank = rank - (int)scan[tid + 1];
        }
        __syncthreads();
        prefix |= ((unsigned)sb) << shift;
        pmask |= 255u << shift;
        rank = srank;
        __syncthreads();
    }
    _Float16* hp = (_Float16*)y;
    const long hb = (long)blockIdx.x * 4096;
#pragma unroll
    for (int j = 0; j < 8; ++j) {
        const int i = j * 256 + tid;
        const float hv = (u[j] >= prefix) ? v[j] : 0.f;
        const _Float16 hi = (_Float16)hv;
        hp[hb + i] = hi;
        hp[hb + 2048 + i] = (_Float16)(hv - (float)hi);
    }
}

// ---------------------------------------------------------------------------
extern "C" void kernel_launch(void* const* d_in, const int* in_sizes, int n_in,
                              void* d_out, int out_size, void* d_ws, size_t ws_size,
                              hipStream_t stream) {
    const float* x    = (const float*)d_in[0];
    const float* ctx  = (const float*)d_in[1];
    const float* w1   = (const float*)d_in[2];
    const float* b1   = (const float*)d_in[3];
    const float* seg1 = (const float*)d_in[4];
    const float* w2   = (const float*)d_in[5];
    const float* b2   = (const float*)d_in[6];
    const float* seg2 = (const float*)d_in[7];
    const float* wo   = (const float*)d_in[8];
    const float* bo   = (const float*)d_in[9];

    char* W = (char*)d_ws;  // 96 MB budget (proven safe)
    float*    gates1 = (float*)W;                     // [ 0,32) MB
    float*    gates2 = (float*)(W + (32L << 20));     // [32,64) MB
    _Float16* ppH[2] = {(_Float16*)(W + (64L << 20)),   // 5 MB each
                        (_Float16*)(W + (74L << 20))};
    _Float16* ppL[2] = {(_Float16*)(W + (69L << 20)),
                        (_Float16*)(W + (79L << 20))};  // ends at 84 MB
    float*    yb     = (float*)(W + (64L << 20));     // [64,96), after dends
    float*    yb2    = (float*)W;                     // [ 0,32), after kw1
    (void)ws_size;

    const long CH = 2560L * 1024;  // seg chunk elems (256 h units)

    // chunk 0 split, then 16 dend dispatches (8 per layer), each fusing the
    // next chunk's frag-major split into its epilogue (ping-pong regions).
    split_frag<<<dim3(1280), dim3(256), 0, stream>>>(seg1, ppH[0], ppL[0]);
    for (int e = 0; e < 16; ++e) {
        const float* srcNext =
            (e == 15) ? nullptr
                      : ((e + 1 < 8) ? seg1 + (long)(e + 1) * CH
                                     : seg2 + (long)(e + 1 - 8) * CH);
        dend_gemm<<<dim3(16, 32), dim3(256), 0, stream>>>(
            ctx, ppH[e & 1], ppL[e & 1], (e < 8) ? gates1 : gates2, (e & 7) * 256,
            srcNext, ppH[(e + 1) & 1], ppL[(e + 1) & 1]);
    }
    // layer 1
    gemm_ab<<<dim3(16, 32), dim3(256), 0, stream>>>(x, w1, b1, yb, 2048, 1024);
    kwinners_kernel<<<dim3(4096), dim3(256), 0, stream>>>(yb, gates1);
    // layer 2 (A = h planes interleaved in yb, ldA = 4096 halfwords)
    gemm_adma<<<dim3(16, 32), dim3(256), 0, stream>>>(
        (const _Float16*)yb, (const _Float16*)yb + 2048, 4096, w2, b2, yb2, 2048, 2048);
    kwinners_kernel<<<dim3(4096), dim3(256), 0, stream>>>(yb2, gates2);
    // output layer
    gemm_adma<<<dim3(8, 32), dim3(256), 0, stream>>>(
        (const _Float16*)yb2, (const _Float16*)yb2 + 2048, 4096, wo, bo,
        (float*)d_out, 1024, 2048);
}

// Round 7
// 1400.783 us; speedup vs baseline: 1.2682x; 1.2682x over previous
//
#include <hip/hip_runtime.h>

// ---------------------------------------------------------------------------
// DendriticMLP on MI355X — round 7 (consolidation of measured-best pieces).
// f16 hi/lo split GEMMs (3-term MFMA hh+hl+lh, ~2^-22 rel err): all discrete
// decisions (abs-max gating, top-k) match the fp32 reference.
// vs round 3 (best, 1390): ctx split once; gates region reused; h planes
// written in-place over y (r5/6-proven); prefetch loads moved AFTER the
// second barrier so the MFMA phase covers their latency (r3 issued them just
// before the barrier's vmcnt(0) drain = zero coverage).
// Workspace (96 MB proven): G[0,32) | yb[32,64) | ctx planes[64,80) then
// yb2[64,96).
// ---------------------------------------------------------------------------

#define AS1 __attribute__((address_space(1)))
#define AS3 __attribute__((address_space(3)))

typedef _Float16 f16x8 __attribute__((ext_vector_type(8)));
typedef _Float16 f16x4 __attribute__((ext_vector_type(4)));
typedef float    f32x4 __attribute__((ext_vector_type(4)));

// swizzled halfword offset of logical chunk q (0..3) in row of a [rows][32]
// f16 tile: physical chunk = q ^ ((row>>1)&3) -> frag reads 2-way max (free).
__device__ __forceinline__ int swz(int row, int q) {
    return row * 32 + ((q ^ ((row >> 1) & 3)) << 3);
}

// ---------------------------------------------------------------------------
// split: fp32 -> f16 hi + f16 lo planes (a ~= hi+lo, err ~2^-22 |a|)
// ---------------------------------------------------------------------------
__global__ __launch_bounds__(256) void split_kernel(const float* __restrict__ s,
                                                    _Float16* __restrict__ hi,
                                                    _Float16* __restrict__ lo, int n4) {
    int i = blockIdx.x * 256 + threadIdx.x;
    if (i >= n4) return;
    float4 a = ((const float4*)s)[i];
    f16x4 h, l;
    h.x = (_Float16)a.x; l.x = (_Float16)(a.x - (float)h.x);
    h.y = (_Float16)a.y; l.y = (_Float16)(a.y - (float)h.y);
    h.z = (_Float16)a.z; l.z = (_Float16)(a.z - (float)h.z);
    h.w = (_Float16)a.w; l.w = (_Float16)(a.w - (float)h.w);
    ((f16x4*)hi)[i] = h;
    ((f16x4*)lo)[i] = l;
}

// DMA one 128x32 f16 plane tile into swizzled LDS (wave-uniform base+lane*16).
__device__ __forceinline__ void dma_plane(const _Float16* __restrict__ g, long row0,
                                          int ldHalf, int kcol, _Float16* lds, int tid) {
#pragma unroll
    for (int rep = 0; rep < 2; ++rep) {
        const int s = tid + rep * 256;           // physical 16B slot, 512 total
        const int row = s >> 2, cp = s & 3;
        const int src = cp ^ ((row >> 1) & 3);   // logical chunk at this slot
        const _Float16* gp = g + (row0 + row) * (long)ldHalf + kcol + src * 8;
        __builtin_amdgcn_global_load_lds((const AS1 void*)gp,
                                         (AS3 void*)(lds + ((s & ~63) << 3)), 16, 0, 0);
    }
}

// convert a prefetched float4 to hi/lo f16x4 and store to swizzled LDS planes
__device__ __forceinline__ void cvt_store(const float4 v, int c, _Float16* sH,
                                          _Float16* sL) {
    const int row = c >> 3, hc = c & 7;
    f16x4 h, l;
    h.x = (_Float16)v.x; l.x = (_Float16)(v.x - (float)h.x);
    h.y = (_Float16)v.y; l.y = (_Float16)(v.y - (float)h.y);
    h.z = (_Float16)v.z; l.z = (_Float16)(v.z - (float)h.z);
    h.w = (_Float16)v.w; l.w = (_Float16)(v.w - (float)h.w);
    const int off = row * 32 + (((hc >> 1) ^ ((row >> 1) & 3)) << 3) + ((hc & 1) << 2);
    *(f16x4*)(sH + off) = h;
    *(f16x4*)(sL + off) = l;
}

// ---------------------------------------------------------------------------
// Dendrite GEMM + abs-max gating epilogue (one layer per launch).
// dend[b,n] = ctx[b,:].seg[n,:], n = h*10+s, 20480 rows. Tile 128(b)x160(n)
// = 16 h-groups x 10 segments. ctx planes via DMA; seg fp32 prefetched into
// registers DURING the MFMA phase (post-barrier), split in-kernel.
// Two-barrier K-loop (r4/r5/r6 alternatives all measured worse).
// Epilogue: acc -> LDS [64][160], argmax_s |dend| (strict > = jnp.argmax),
// gates[b][h] = sigmoid(selected), fp32.
// ---------------------------------------------------------------------------
__global__ __launch_bounds__(256) void dend_gemm(const _Float16* __restrict__ AH,
                                                 const _Float16* __restrict__ AL,
                                                 const float* __restrict__ seg,
                                                 float* __restrict__ gates) {
    __shared__ __align__(16) char smem[40960];
    _Float16* sAh = (_Float16*)smem;            //  8192 B (128x32)
    _Float16* sAl = (_Float16*)(smem + 8192);   //  8192 B
    _Float16* sBh = (_Float16*)(smem + 16384);  // 10240 B (160x32)
    _Float16* sBl = (_Float16*)(smem + 26624);  // 10240 B
    float* Cred = (float*)smem;                 // [64][160] epilogue union
    const int tid = threadIdx.x;
    const int w = tid >> 6, lane = tid & 63;
    const int wm = w >> 1, wn = w & 1;
    const int q = lane >> 4, l15 = lane & 15;
    const int bm = blockIdx.y, bn = blockIdx.x;
    const long arow0 = (long)bm * 128, brow0 = (long)bn * 160;
    f32x4 acc[4][5] = {};
    float4 pre[5];
    auto loadB = [&](int kt) {
#pragma unroll
        for (int j = 0; j < 5; ++j) {
            const int c = tid + j * 256;
            pre[j] = *(const float4*)(seg + (brow0 + (c >> 3)) * 1024L + (kt << 5) +
                                      ((c & 7) << 2));
        }
    };
    loadB(0);
    for (int kt = 0; kt < 32; ++kt) {
        __syncthreads();  // frag reads of kt-1 complete (drains pre-loads too)
        // writeB first: its vmcnt wait covers only pre (landed during MFMA),
        // not the A-DMA issued below.
#pragma unroll
        for (int j = 0; j < 5; ++j) cvt_store(pre[j], tid + j * 256, sBh, sBl);
        const int kcol = kt << 5;
        dma_plane(AH, arow0, 1024, kcol, sAh, tid);
        dma_plane(AL, arow0, 1024, kcol, sAl, tid);
        __syncthreads();  // drains ds_writes + A-DMA
        if (kt < 31) loadB(kt + 1);  // post-barrier: latency covered by MFMA
        f16x8 aH[4], aL[4];
#pragma unroll
        for (int tm = 0; tm < 4; ++tm) {
            const int row = wm * 64 + tm * 16 + l15;
            aH[tm] = *(const f16x8*)&sAh[swz(row, q)];
            aL[tm] = *(const f16x8*)&sAl[swz(row, q)];
        }
#pragma unroll
        for (int tn = 0; tn < 5; ++tn) {
            const int rowb = wn * 80 + tn * 16 + l15;
            const f16x8 bH = *(const f16x8*)&sBh[swz(rowb, q)];
            const f16x8 bL = *(const f16x8*)&sBl[swz(rowb, q)];
#pragma unroll
            for (int tm = 0; tm < 4; ++tm) {
                acc[tm][tn] = __builtin_amdgcn_mfma_f32_16x16x32_f16(aH[tm], bH, acc[tm][tn], 0, 0, 0);
                acc[tm][tn] = __builtin_amdgcn_mfma_f32_16x16x32_f16(aH[tm], bL, acc[tm][tn], 0, 0, 0);
                acc[tm][tn] = __builtin_amdgcn_mfma_f32_16x16x32_f16(aL[tm], bH, acc[tm][tn], 0, 0, 0);
            }
        }
    }
    // epilogue: two 64-row chunks through LDS ([64][160]: hh*10 mod 32 distinct)
    for (int c = 0; c < 2; ++c) {
        __syncthreads();
        if (wm == c) {
#pragma unroll
            for (int tm = 0; tm < 4; ++tm)
#pragma unroll
                for (int tn = 0; tn < 5; ++tn)
#pragma unroll
                    for (int r = 0; r < 4; ++r)
                        Cred[(tm * 16 + q * 4 + r) * 160 + wn * 80 + tn * 16 + l15] =
                            acc[tm][tn][r];
        }
        __syncthreads();
        for (int p = tid; p < 1024; p += 256) {
            const int bb = p >> 4, hh = p & 15;
            const float* d = &Cred[bb * 160 + hh * 10];
            float best = d[0], ba = fabsf(d[0]);
#pragma unroll
            for (int s = 1; s < 10; ++s) {
                const float v = d[s], a = fabsf(v);
                if (a > ba) { ba = a; best = v; }  // strict >: first occurrence
            }
            const float gate = 1.f / (1.f + expf(-best));
            const int bg = bm * 128 + c * 64 + bb;
            const int h = bn * 16 + hh;
            gates[(long)bg * 2048 + h] = gate;
        }
    }
}

// ---------------------------------------------------------------------------
// GEMM, A = f16 hi/lo planes with row stride ldA halfwords (kwinners'
// row-interleaved layout), DMA-staged; B fp32 (post-barrier prefetch +
// in-kernel split). C[M,N] = A @ B[N,K]^T + bias.
// ---------------------------------------------------------------------------
__global__ __launch_bounds__(256) void gemm_adma(
    const _Float16* __restrict__ AH, const _Float16* __restrict__ AL, int ldA,
    const float* __restrict__ B, const float* __restrict__ bias,
    float* __restrict__ C, int N, int K) {
    __shared__ __align__(16) _Float16 sAh[4096], sAl[4096], sBh[4096], sBl[4096];
    const int tid = threadIdx.x;
    const int w = tid >> 6, lane = tid & 63;
    const int wm = w >> 1, wn = w & 1;
    const int q = lane >> 4, l15 = lane & 15;
    const int bm = blockIdx.y, bn = blockIdx.x;
    const long arow0 = (long)bm * 128, brow0 = (long)bn * 128;
    f32x4 acc[4][4] = {};
    float4 pre[4];
    auto loadB = [&](int kt) {
#pragma unroll
        for (int j = 0; j < 4; ++j) {
            const int c = tid + j * 256;
            pre[j] = *(const float4*)(B + (brow0 + (c >> 3)) * (long)K + (kt << 5) +
                                      ((c & 7) << 2));
        }
    };
    loadB(0);
    const int ksteps = K >> 5;
    for (int kt = 0; kt < ksteps; ++kt) {
        __syncthreads();
#pragma unroll
        for (int j = 0; j < 4; ++j) cvt_store(pre[j], tid + j * 256, sBh, sBl);
        const int kcol = kt << 5;
        dma_plane(AH, arow0, ldA, kcol, sAh, tid);
        dma_plane(AL, arow0, ldA, kcol, sAl, tid);
        __syncthreads();
        if (kt + 1 < ksteps) loadB(kt + 1);  // post-barrier prefetch
        f16x8 aH[4], aL[4];
#pragma unroll
        for (int tm = 0; tm < 4; ++tm) {
            const int row = wm * 64 + tm * 16 + l15;
            aH[tm] = *(const f16x8*)&sAh[swz(row, q)];
            aL[tm] = *(const f16x8*)&sAl[swz(row, q)];
        }
#pragma unroll
        for (int tn = 0; tn < 4; ++tn) {
            const int rowb = wn * 64 + tn * 16 + l15;
            const f16x8 bH = *(const f16x8*)&sBh[swz(rowb, q)];
            const f16x8 bL = *(const f16x8*)&sBl[swz(rowb, q)];
#pragma unroll
            for (int tm = 0; tm < 4; ++tm) {
                acc[tm][tn] = __builtin_amdgcn_mfma_f32_16x16x32_f16(aH[tm], bH, acc[tm][tn], 0, 0, 0);
                acc[tm][tn] = __builtin_amdgcn_mfma_f32_16x16x32_f16(aH[tm], bL, acc[tm][tn], 0, 0, 0);
                acc[tm][tn] = __builtin_amdgcn_mfma_f32_16x16x32_f16(aL[tm], bH, acc[tm][tn], 0, 0, 0);
            }
        }
    }
    float bv[4];
#pragma unroll
    for (int tn = 0; tn < 4; ++tn) bv[tn] = bias[bn * 128 + wn * 64 + tn * 16 + l15];
#pragma unroll
    for (int tm = 0; tm < 4; ++tm) {
        const int m0 = bm * 128 + wm * 64 + tm * 16 + q * 4;
#pragma unroll
        for (int tn = 0; tn < 4; ++tn) {
            const int n = bn * 128 + wn * 64 + tn * 16 + l15;
#pragma unroll
            for (int r = 0; r < 4; ++r)
                C[(long)(m0 + r) * N + n] = acc[tm][tn][r] + bv[tn];
        }
    }
}

// ---------------------------------------------------------------------------
// GEMM, A and B both fp32, no DMA (layer 1: x @ w1^T). All global loads
// issue post-barrier during the MFMA phase; the staging barrier waits only
// on lgkmcnt (ds_writes) — tests the no-DMA hypothesis.
// ---------------------------------------------------------------------------
__global__ __launch_bounds__(256) void gemm_ab(
    const float* __restrict__ A, const float* __restrict__ B,
    const float* __restrict__ bias, float* __restrict__ C, int N, int K) {
    __shared__ __align__(16) _Float16 sAh[4096], sAl[4096], sBh[4096], sBl[4096];
    const int tid = threadIdx.x;
    const int w = tid >> 6, lane = tid & 63;
    const int wm = w >> 1, wn = w & 1;
    const int q = lane >> 4, l15 = lane & 15;
    const int bm = blockIdx.y, bn = blockIdx.x;
    const long arow0 = (long)bm * 128, brow0 = (long)bn * 128;
    f32x4 acc[4][4] = {};
    float4 preA[4], preB[4];
    auto loadAB = [&](int kt) {
#pragma unroll
        for (int j = 0; j < 4; ++j) {
            const int c = tid + j * 256;
            preA[j] = *(const float4*)(A + (arow0 + (c >> 3)) * (long)K + (kt << 5) +
                                       ((c & 7) << 2));
            preB[j] = *(const float4*)(B + (brow0 + (c >> 3)) * (long)K + (kt << 5) +
                                       ((c & 7) << 2));
        }
    };
    loadAB(0);
    const int ksteps = K >> 5;
    for (int kt = 0; kt < ksteps; ++kt) {
        __syncthreads();
#pragma unroll
        for (int j = 0; j < 4; ++j) {
            cvt_store(preA[j], tid + j * 256, sAh, sAl);
            cvt_store(preB[j], tid + j * 256, sBh, sBl);
        }
        __syncthreads();
        if (kt + 1 < ksteps) loadAB(kt + 1);  // post-barrier prefetch
        f16x8 aH[4], aL[4];
#pragma unroll
        for (int tm = 0; tm < 4; ++tm) {
            const int row = wm * 64 + tm * 16 + l15;
            aH[tm] = *(const f16x8*)&sAh[swz(row, q)];
            aL[tm] = *(const f16x8*)&sAl[swz(row, q)];
        }
#pragma unroll
        for (int tn = 0; tn < 4; ++tn) {
            const int rowb = wn * 64 + tn * 16 + l15;
            const f16x8 bH = *(const f16x8*)&sBh[swz(rowb, q)];
            const f16x8 bL = *(const f16x8*)&sBl[swz(rowb, q)];
#pragma unroll
            for (int tm = 0; tm < 4; ++tm) {
                acc[tm][tn] = __builtin_amdgcn_mfma_f32_16x16x32_f16(aH[tm], bH, acc[tm][tn], 0, 0, 0);
                acc[tm][tn] = __builtin_amdgcn_mfma_f32_16x16x32_f16(aH[tm], bL, acc[tm][tn], 0, 0, 0);
                acc[tm][tn] = __builtin_amdgcn_mfma_f32_16x16x32_f16(aL[tm], bH, acc[tm][tn], 0, 0, 0);
            }
        }
    }
    float bv[4];
#pragma unroll
    for (int tn = 0; tn < 4; ++tn) bv[tn] = bias[bn * 128 + wn * 64 + tn * 16 + l15];
#pragma unroll
    for (int tm = 0; tm < 4; ++tm) {
        const int m0 = bm * 128 + wm * 64 + tm * 16 + q * 4;
#pragma unroll
        for (int tn = 0; tn < 4; ++tn) {
            const int n = bn * 128 + wn * 64 + tn * 16 + l15;
#pragma unroll
            for (int r = 0; r < 4; ++r)
                C[(long)(m0 + r) * N + n] = acc[tm][tn][r] + bv[tn];
        }
    }
}

// ---------------------------------------------------------------------------
// KWinners: v = y*gate (fp32); exact 102nd-largest via radix select on
// order-preserving uint keys; keep where key >= kth (jnp tie semantics).
// Writes h planes IN PLACE over y, row-interleaved (hi | lo per 8 KB row);
// one block owns one row, reads complete before writes.
// ---------------------------------------------------------------------------
__global__ __launch_bounds__(256) void kwinners_kernel(float* __restrict__ y,
                                                       const float* __restrict__ g) {
    __shared__ unsigned hist[256];
    __shared__ unsigned scan[257];
    __shared__ int sb, srank;
    const int tid = threadIdx.x;
    const long base = (long)blockIdx.x * 2048;
    float v[8];
    unsigned u[8];
#pragma unroll
    for (int j = 0; j < 8; ++j) {
        const int i = j * 256 + tid;
        const float val = y[base + i] * g[base + i];
        v[j] = val;
        const unsigned b = __float_as_uint(val);
        u[j] = b ^ (unsigned)((((int)b) >> 31) | 0x80000000);  // monotone map
    }
    unsigned prefix = 0, pmask = 0;
    int rank = 102;
    for (int round = 0; round < 4; ++round) {
        const int shift = 24 - (round << 3);
        hist[tid] = 0;
        if (tid == 0) scan[256] = 0;
        __syncthreads();
#pragma unroll
        for (int j = 0; j < 8; ++j)
            if ((u[j] & pmask) == prefix) atomicAdd(&hist[(u[j] >> shift) & 255], 1u);
        __syncthreads();
        scan[tid] = hist[tid];
        __syncthreads();
        for (int off = 1; off < 256; off <<= 1) {  // inclusive suffix sum
            const unsigned t = scan[tid] + ((tid + off < 256) ? scan[tid + off] : 0u);
            __syncthreads();
            scan[tid] = t;
            __syncthreads();
        }
        if (scan[tid] >= (unsigned)rank && scan[tid + 1] < (unsigned)rank) {
            sb = tid;
            srank = rank - (int)scan[tid + 1];
        }
        __syncthreads();
        prefix |= ((unsigned)sb) << shift;
        pmask |= 255u << shift;
        rank = srank;
        __syncthreads();
    }
    _Float16* hp = (_Float16*)y;
    const long hb = (long)blockIdx.x * 4096;
#pragma unroll
    for (int j = 0; j < 8; ++j) {
        const int i = j * 256 + tid;
        const float hv = (u[j] >= prefix) ? v[j] : 0.f;
        const _Float16 hi = (_Float16)hv;
        hp[hb + i] = hi;
        hp[hb + 2048 + i] = (_Float16)(hv - (float)hi);
    }
}

// ---------------------------------------------------------------------------
extern "C" void kernel_launch(void* const* d_in, const int* in_sizes, int n_in,
                              void* d_out, int out_size, void* d_ws, size_t ws_size,
                              hipStream_t stream) {
    const float* x    = (const float*)d_in[0];
    const float* ctx  = (const float*)d_in[1];
    const float* w1   = (const float*)d_in[2];
    const float* b1   = (const float*)d_in[3];
    const float* seg1 = (const float*)d_in[4];
    const float* w2   = (const float*)d_in[5];
    const float* b2   = (const float*)d_in[6];
    const float* seg2 = (const float*)d_in[7];
    const float* wo   = (const float*)d_in[8];
    const float* bo   = (const float*)d_in[9];

    // 96 MB (proven), time-multiplexed:
    //  G   [ 0,32): gates layer1, then (after kw1) gates layer2
    //  yb  [32,64): y1, then h1 planes in place
    //  ctx planes [64,80): alive through dend2
    //  yb2 [64,96): y2, then h2 planes in place (after ctx dies)
    char* W = (char*)d_ws;
    float*    G    = (float*)W;
    float*    yb   = (float*)(W + (32L << 20));
    _Float16* ctxH = (_Float16*)(W + (64L << 20));
    _Float16* ctxL = (_Float16*)(W + (72L << 20));
    float*    yb2  = (float*)(W + (64L << 20));
    (void)ws_size;

    split_kernel<<<dim3(4096), dim3(256), 0, stream>>>(ctx, ctxH, ctxL,
                                                       (4096 * 1024) / 4);
    // layer 1
    dend_gemm<<<dim3(128, 32), dim3(256), 0, stream>>>(ctxH, ctxL, seg1, G);
    gemm_ab<<<dim3(16, 32), dim3(256), 0, stream>>>(x, w1, b1, yb, 2048, 1024);
    kwinners_kernel<<<dim3(4096), dim3(256), 0, stream>>>(yb, G);
    // layer 2 (G region reused; ctx planes still alive for dend2)
    dend_gemm<<<dim3(128, 32), dim3(256), 0, stream>>>(ctxH, ctxL, seg2, G);
    gemm_adma<<<dim3(16, 32), dim3(256), 0, stream>>>(
        (const _Float16*)yb, (const _Float16*)yb + 2048, 4096, w2, b2, yb2, 2048, 2048);
    kwinners_kernel<<<dim3(4096), dim3(256), 0, stream>>>(yb2, G);
    // output layer
    gemm_adma<<<dim3(8, 32), dim3(256), 0, stream>>>(
        (const _Float16*)yb2, (const _Float16*)yb2 + 2048, 4096, wo, bo,
        (float*)d_out, 1024, 2048);
}